// Round 1
// baseline (22.397 us; speedup 1.0000x reference)
//
#include <hip/hip_runtime.h>

#define BATCH  128
#define NB     14
#define TS     1096          // num_time_samples
#define LTOT   24            // channel length
#define FRAME  (TS + LTOT - 1)          // 1119
#define OUTLEN ((NB - 1) * TS + FRAME)  // 15367

// Gather formulation: each thread computes exactly one output sample.
// out[b, o] = sum over the (<=2) frames n whose OLA window covers o of
//             sum_j h[b,n,j] * x[b,n, (o - n*T) - j]
__global__ __launch_bounds__(256)
void atc_gather_kernel(const float* __restrict__ x,
                       const float* __restrict__ h,
                       float* __restrict__ out) {
    const int o = blockIdx.x * blockDim.x + threadIdx.x;
    const int b = blockIdx.y;
    if (o >= OUTLEN) return;

    int n1 = o / TS;
    if (n1 > NB - 1) n1 = NB - 1;          // tail samples belong to last frame
    const int i1 = o - n1 * TS;            // local index in frame n1, in [0, FRAME)

    float acc = 0.0f;

    // --- frame n1 contribution: taps j with 0 <= i1 - j < TS ---
    {
        const float* __restrict__ xb = x + ((size_t)b * NB + n1) * TS;
        const float* __restrict__ hb = h + ((size_t)b * NB + n1) * LTOT;
        if (i1 >= LTOT - 1 && i1 <= TS - 1) {
            // interior: full 24-tap window, unrolled
            #pragma unroll
            for (int j = 0; j < LTOT; ++j)
                acc = fmaf(hb[j], xb[i1 - j], acc);
        } else {
            int jlo = i1 - (TS - 1); if (jlo < 0) jlo = 0;
            int jhi = i1 < LTOT - 1 ? i1 : LTOT - 1;
            for (int j = jlo; j <= jhi; ++j)
                acc = fmaf(hb[j], xb[i1 - j], acc);
        }
    }

    // --- frame n1-1 contribution (overlap seam): only when i1 < LTOT-1 ---
    if (i1 < LTOT - 1 && n1 > 0) {
        const int n0 = n1 - 1;
        const int i0 = i1 + TS;            // local index in frame n0, in [TS, FRAME)
        const float* __restrict__ xb = x + ((size_t)b * NB + n0) * TS;
        const float* __restrict__ hb = h + ((size_t)b * NB + n0) * LTOT;
        const int jlo = i0 - (TS - 1);     // >= 1
        for (int j = jlo; j < LTOT; ++j)
            acc = fmaf(hb[j], xb[i0 - j], acc);
    }

    out[(size_t)b * OUTLEN + o] = acc;
}

extern "C" void kernel_launch(void* const* d_in, const int* in_sizes, int n_in,
                              void* d_out, int out_size, void* d_ws, size_t ws_size,
                              hipStream_t stream) {
    const float* x = (const float*)d_in[0];   // [B, NB, TS]
    const float* h = (const float*)d_in[1];   // [B, NB, LTOT]
    float* out = (float*)d_out;               // [B, OUTLEN]

    dim3 block(256, 1, 1);
    dim3 grid((OUTLEN + 255) / 256, BATCH, 1);
    atc_gather_kernel<<<grid, block, 0, stream>>>(x, h, out);
}